// Round 9
// baseline (219.972 us; speedup 1.0000x reference)
//
#include <hip/hip_runtime.h>
#include <stdint.h>

#define B_  2
#define S_  2048
#define D_  1024
#define H_  16
#define DK_ 64
#define VST 2176   // q2T padded row stride (4352 B = 17*256): breaks 4KB aliasing

typedef unsigned short u16;
typedef short bf16x8 __attribute__((ext_vector_type(8)));
typedef float f32x4  __attribute__((ext_vector_type(4)));

#define MFMA(a,b,c) __builtin_amdgcn_mfma_f32_16x16x32_bf16((a),(b),(c),0,0,0)
#define EXP2(x) __builtin_amdgcn_exp2f(x)

static __device__ __forceinline__ u16 f2bf(float f) {
    uint32_t u = __float_as_uint(f);
    u += 0x7fffu + ((u >> 16) & 1u);   // RNE
    return (u16)(u >> 16);
}
static __device__ __forceinline__ uint32_t pk2(float x, float y) {
    return __builtin_amdgcn_perm(__float_as_uint(y) + 0x8000u,
                                 __float_as_uint(x) + 0x8000u, 0x07060302u);
}

typedef const __attribute__((address_space(1))) void* gas_p;
typedef __attribute__((address_space(3))) void* las_p;
static __device__ __forceinline__ void gld16(const void* g, void* l) {
    __builtin_amdgcn_global_load_lds((gas_p)g, (las_p)l, 16, 0, 0);
}

// ---------------- one fused f32 -> bf16 conversion pass ----------------
// bf16 arena layout (u16 element offsets):
//   vb 0 | kb 4194304 | qb 8388608 | Wvb 12582912 | Wkb 13631488
//   Wqb 14680064 | Wob 15728640     (total 16M u16 = 32 MB)

__global__ void conv_all(const float* __restrict__ v, const float* __restrict__ k,
                         const float* __restrict__ q,
                         const float* __restrict__ Wv, const float* __restrict__ Wk,
                         const float* __restrict__ Wq, const float* __restrict__ Wo,
                         u16* __restrict__ dst) {
    const int b = blockIdx.x;
    const float* s;
    size_t loc, segbase;
    if (b < 12288) {                          // 3 X tensors, 4096 blocks each
        const int t = b >> 12;
        s = (t == 0) ? v : (t == 1 ? k : q);
        segbase = (size_t)t * 4194304;
        loc = (size_t)(b & 4095) * 1024;
    } else {                                  // 4 W tensors, 1024 blocks each
        const int t = (b - 12288) >> 10;
        s = (t == 0) ? Wv : (t == 1 ? Wk : (t == 2 ? Wq : Wo));
        segbase = 12582912 + (size_t)t * 1048576;
        loc = (size_t)(b & 1023) * 1024;
    }
    loc += threadIdx.x * 4;
    float4 f = *(const float4*)(s + loc);
    ushort4 o;
    o.x = f2bf(f.x); o.y = f2bf(f.y); o.z = f2bf(f.z); o.w = f2bf(f.w);
    *(ushort4*)(dst + segbase + loc) = o;
}

// ---------------- projection GEMMs: C = X @ W^T + bias (bf16) ----------------
// BK=32, single-barrier double-buffered K-loop (flash-proven pattern):
// prologue stages tile 0; each iter: barrier (drains stage(it)), issue
// stage(it+1) into the other buffer, compute(it). 4-chunk XOR swizzle
// (2-way max aliasing = free). Epi overlays loop bufs after a barrier.
// z=0: v -> v2 (B,H,S,DK), scaled 0.125*log2(e).  z=1: k -> k2.
// z=2: q -> q2T (B,H,DK,S) padded stride VST.  XCD-grouped block remap.

__global__ __launch_bounds__(256) void proj_gemm(
    const u16* __restrict__ Xb, const u16* __restrict__ Wb,
    const float* __restrict__ bv, const float* __restrict__ bk, const float* __restrict__ bq,
    u16* __restrict__ v2, u16* __restrict__ k2, u16* __restrict__ q2T)
{
    __shared__ alignas(16) char smem[40960];   // lA[2]8K + lB[2]8K; epi overlay 40K
    u16* lA = (u16*)smem;                      // [buf][128*32]
    u16* lB = (u16*)(smem + 16384);
    u16* epi = (u16*)smem;                     // [wave][64][80] u16 (after barrier)

    const int z = blockIdx.z;
    const u16* A = Xb + (size_t)z * 4194304;   // v / k / q (bf16)
    const u16* W = Wb + (size_t)z * 1048576;   // Wv / Wk / Wq (bf16)
    const float* bias = (z == 0) ? bv : (z == 1 ? bk : bq);

    const int tid = threadIdx.x;
    const int lane = tid & 63, wave = tid >> 6;
    const int wm = wave >> 1, wn = wave & 1;
    const int q = lane >> 4, l15 = lane & 15;
    const int q4 = q * 4;

    // XCD grouping: f = y*8+x; M-block = f&31 keys the XCD
    const int f = blockIdx.y * 8 + blockIdx.x;
    const int rowbase = (f & 31) * 128;
    const int colbase = (f >> 5) * 128;

    // staging: 16 rows/wave per issue (j=0: rows 0-63, j=1: 64-127);
    // 4 chunks of 16B per 32-u16 row, chunk XOR-swizzled by row&3
    const int srow = wave * 16 + (lane >> 2);
    const int cg = (lane & 3) ^ ((lane >> 2) & 3);
    const u16* gA = A + (size_t)(rowbase + srow) * D_ + cg * 8;
    const u16* gW = W + (size_t)(colbase + srow) * D_ + cg * 8;
    const int sdst = wave * 512 + lane * 8;    // lane-contiguous 16B dest

    const int fo0 = (q ^ (l15 & 3)) * 8;       // fragment chunk (de-swizzle)

    f32x4 acc[4][4] = {};

    // prologue: stage k-tile 0 into buf 0
    gld16(gA,           lA + sdst);
    gld16(gA + 64 * D_, lA + 2048 + sdst);
    gld16(gW,           lB + sdst);
    gld16(gW + 64 * D_, lB + 2048 + sdst);

    for (int it = 0; it < 32; ++it) {
        const int buf = it & 1;
        __syncthreads();   // drains vmcnt: stage(it) ready; buf^1 free to overwrite
        if (it + 1 < 32) {
            const int k1 = (it + 1) * 32;
            const int ob = (buf ^ 1) * 4096;
            gld16(gA + k1,           lA + ob + sdst);
            gld16(gA + k1 + 64 * D_, lA + ob + 2048 + sdst);
            gld16(gW + k1,           lB + ob + sdst);
            gld16(gW + k1 + 64 * D_, lB + ob + 2048 + sdst);
        }
        bf16x8 af[4], bfr[4];
        #pragma unroll
        for (int mi = 0; mi < 4; mi++)
            af[mi] = *(const bf16x8*)&lA[buf * 4096 + (wm * 64 + mi * 16 + l15) * 32 + fo0];
        #pragma unroll
        for (int ni = 0; ni < 4; ni++)
            bfr[ni] = *(const bf16x8*)&lB[buf * 4096 + (wn * 64 + ni * 16 + l15) * 32 + fo0];
        #pragma unroll
        for (int mi = 0; mi < 4; mi++)
            #pragma unroll
            for (int ni = 0; ni < 4; ni++)
                acc[mi][ni] = MFMA(af[mi], bfr[ni], acc[mi][ni]);
    }
    __syncthreads();   // all waves done with loop bufs before epi overlay

    // ---- epilogue via per-wave LDS transpose (stride 80 u16) ----
    u16* ep = epi + wave * (64 * 80);
    const int h = (colbase + wn * 64) >> 6;
    const int Mrow0 = rowbase + wm * 64;
    const int bb = Mrow0 >> 11;

    if (z < 2) {
        u16* outp = (z == 0) ? v2 : k2;
        const float scale = (z == 0) ? 0.18033688011112042f : 1.0f;  // 0.125*log2(e)
        #pragma unroll
        for (int mi = 0; mi < 4; mi++)
            #pragma unroll
            for (int ni = 0; ni < 4; ni++) {
                const float bc = bias[colbase + wn * 64 + ni * 16 + l15];
                #pragma unroll
                for (int rg = 0; rg < 4; rg++)
                    ep[(mi * 16 + q4 + rg) * 80 + ni * 16 + l15] =
                        f2bf((acc[mi][ni][rg] + bc) * scale);
            }
        asm volatile("s_waitcnt lgkmcnt(0)" ::: "memory");
        const int s = (Mrow0 + lane) & (S_ - 1);
        u16* gb = outp + ((size_t)(bb * H_ + h) * S_ + s) * DK_;
        #pragma unroll
        for (int j = 0; j < 8; j++)
            *(uint4*)(gb + j * 8) = *(const uint4*)&ep[lane * 80 + j * 8];
    } else {
        #pragma unroll
        for (int mi = 0; mi < 4; mi++)
            #pragma unroll
            for (int ni = 0; ni < 4; ni++) {
                const float bc = bias[colbase + wn * 64 + ni * 16 + l15];
                uint2 pk;
                pk.x = pk2(acc[mi][ni][0] + bc, acc[mi][ni][1] + bc);
                pk.y = pk2(acc[mi][ni][2] + bc, acc[mi][ni][3] + bc);
                *(uint2*)&ep[(ni * 16 + l15) * 80 + mi * 16 + q4] = pk;
            }
        asm volatile("s_waitcnt lgkmcnt(0)" ::: "memory");
        const int s0g = Mrow0 & (S_ - 1);
        u16* gb = q2T + ((size_t)(bb * H_ + h) * DK_ + lane) * VST + s0g;
        #pragma unroll
        for (int j = 0; j < 8; j++)
            *(uint4*)(gb + j * 8) = *(const uint4*)&ep[lane * 80 + j * 8];
    }
}

// ---------------- flash attention v4 (verbatim from R8) ----------------
// Roles (source bug): "query"=v2 (prescaled, log2 domain), "key"=k2, "value"=q2.

__global__ __launch_bounds__(512, 2) void flash_attn(
    const u16* __restrict__ v2, const u16* __restrict__ k2,
    const u16* __restrict__ q2T, u16* __restrict__ Ob)
{
    __shared__ alignas(16) char smem[82944];
    u16* lK   = (u16*)smem;                  // [th 2][buf 2][64*64]
    u16* lV   = (u16*)(smem + 32768);        // [th 2][buf 2][64*64]
    u16* ldsP = (u16*)(smem + 65536);        // [wave 8][16][68]
    float* Xo = (float*)smem;                // epilogue overlay: [wl 4][64][68] f32
    float* Xl = (float*)(smem + 69632);      // [256] f32

    const int tid = threadIdx.x;
    const int lane = tid & 63, wave = tid >> 6;
    const int th = wave >> 2, wl = wave & 3;
    const int q = lane >> 4, l15 = lane & 15;
    const int q4 = q * 4;
    const int bh = blockIdx.x & 31;
    const int sbase = (blockIdx.x >> 5) * 256;
    const int tbase = th * 1024;

    const u16* Qp = v2  + (size_t)bh * S_ * DK_;
    const u16* Kp = k2  + (size_t)bh * S_ * DK_;
    const u16* Vp = q2T + (size_t)bh * DK_ * VST;

    const int srow8 = lane >> 3;
    const int cs    = lane & 7;
    const int cg    = cs ^ srow8;
    const int krow0 = wl * 16 + srow8;
    u16* lKh = lK + th * 8192;
    u16* lVh = lV + th * 8192;

    bf16x8 bq[4][2];
    #pragma unroll
    for (int g = 0; g < 4; g++) {
        const u16* qp = Qp + (size_t)(sbase + wl * 64 + g * 16 + l15) * DK_ + q * 8;
        bq[g][0] = *(const bf16x8*)(qp);
        bq[g][1] = *(const bf16x8*)(qp + 32);
    }

    bf16x8 ones;
    #pragma unroll
    for (int i = 0; i < 8; i++) ones[i] = (short)0x3F80;

    f32x4 o_acc[4][4] = {};
    f32x4 o_l[4] = {};

    const int sw = l15 & 7;
    const int fc0 = (q ^ sw) * 8;
    const int fc1 = fc0 ^ 32;

    {
        const u16* kg = Kp + (size_t)(tbase + krow0) * DK_ + cg * 8;
        const u16* vg = Vp + (size_t)krow0 * VST + tbase + cg * 8;
        u16* lkd = lKh + wl * 1024 + lane * 8;
        u16* lvd = lVh + wl * 1024 + lane * 8;
        gld16(kg, lkd);
        gld16(kg + 8 * DK_, lkd + 512);
        gld16(vg, lvd);
        gld16(vg + (size_t)8 * VST, lvd + 512);
    }

    u16* Pw = ldsP + wave * (16 * 68);

    for (int it = 0; it < 16; ++it) {
        const int buf = it & 1;
        __syncthreads();
        if (it + 1 < 16) {
            const int t1 = tbase + (it + 1) * 64;
            const u16* kg = Kp + (size_t)(t1 + krow0) * DK_ + cg * 8;
            const u16* vg = Vp + (size_t)krow0 * VST + t1 + cg * 8;
            u16* lkd = lKh + (buf ^ 1) * 4096 + wl * 1024 + lane * 8;
            u16* lvd = lVh + (buf ^ 1) * 4096 + wl * 1024 + lane * 8;
            gld16(kg, lkd);
            gld16(kg + 8 * DK_, lkd + 512);
            gld16(vg, lvd);
            gld16(vg + (size_t)8 * VST, lvd + 512);
        }

        const u16* Kt = lKh + buf * 4096;
        const u16* Vt = lVh + buf * 4096;
        bf16x8 ak0[4], ak1[4], av0[4], av1[4];
        #pragma unroll
        for (int mi = 0; mi < 4; mi++) {
            const int r = (mi * 16 + l15) * 64;
            ak0[mi] = *(const bf16x8*)&Kt[r + fc0];
            ak1[mi] = *(const bf16x8*)&Kt[r + fc1];
            av0[mi] = *(const bf16x8*)&Vt[r + fc0];
            av1[mi] = *(const bf16x8*)&Vt[r + fc1];
        }

        #pragma unroll
        for (int g = 0; g < 4; g++) {
            f32x4 sa[4];
            #pragma unroll
            for (int mi = 0; mi < 4; mi++) {
                f32x4 zz = {};
                zz = MFMA(ak0[mi], bq[g][0], zz);
                sa[mi] = MFMA(ak1[mi], bq[g][1], zz);
            }
            #pragma unroll
            for (int mi = 0; mi < 4; mi++) {
                float p0 = EXP2(sa[mi][0]);
                float p1 = EXP2(sa[mi][1]);
                float p2 = EXP2(sa[mi][2]);
                float p3 = EXP2(sa[mi][3]);
                uint2 pk;
                pk.x = __builtin_amdgcn_perm(__float_as_uint(p1), __float_as_uint(p0), 0x07060302u);
                pk.y = __builtin_amdgcn_perm(__float_as_uint(p3), __float_as_uint(p2), 0x07060302u);
                *(uint2*)&Pw[l15 * 68 + mi * 16 + q4] = pk;
            }
            asm volatile("s_waitcnt lgkmcnt(0)" ::: "memory");
            bf16x8 bp0, bp1;
            {
                uint2* r0 = (uint2*)&bp0;
                r0[0] = *(const uint2*)&Pw[l15 * 68 + q * 8];
                r0[1] = *(const uint2*)&Pw[l15 * 68 + q * 8 + 4];
                uint2* r1 = (uint2*)&bp1;
                r1[0] = *(const uint2*)&Pw[l15 * 68 + 32 + q * 8];
                r1[1] = *(const uint2*)&Pw[l15 * 68 + 32 + q * 8 + 4];
            }
            #pragma unroll
            for (int mi = 0; mi < 4; mi++) {
                o_acc[g][mi] = MFMA(av0[mi], bp0, o_acc[g][mi]);
                o_acc[g][mi] = MFMA(av1[mi], bp1, o_acc[g][mi]);
            }
            o_l[g] = MFMA(ones, bp0, o_l[g]);
            o_l[g] = MFMA(ones, bp1, o_l[g]);
        }
    }

    __syncthreads();
    if (th == 1) {
        #pragma unroll
        for (int g = 0; g < 4; g++) {
            const int sr = wl * 64 + g * 16 + l15;
            #pragma unroll
            for (int mi = 0; mi < 4; mi++)
                *(f32x4*)&Xo[sr * 68 + mi * 16 + q4] = o_acc[g][mi];
            if (q == 0) Xl[sr] = o_l[g][0];
        }
    }
    __syncthreads();
    if (th == 0) {
        const int bb = bh >> 4, h = bh & 15;
        #pragma unroll
        for (int g = 0; g < 4; g++) {
            const int sr = wl * 64 + g * 16 + l15;
            const float inv_l = 1.0f / (o_l[g][0] + Xl[sr]);
            const int s = sbase + sr;
            #pragma unroll
            for (int mi = 0; mi < 4; mi++) {
                f32x4 p = *(const f32x4*)&Xo[sr * 68 + mi * 16 + q4];
                ushort4 o4;
                o4.x = f2bf((o_acc[g][mi][0] + p[0]) * inv_l);
                o4.y = f2bf((o_acc[g][mi][1] + p[1]) * inv_l);
                o4.z = f2bf((o_acc[g][mi][2] + p[2]) * inv_l);
                o4.w = f2bf((o_acc[g][mi][3] + p[3]) * inv_l);
                *(ushort4*)(Ob + (size_t)(bb * S_ + s) * (H_ * DK_) + h * DK_ + mi * 16 + q4) = o4;
            }
        }
    }
}

// ---------------- output GEMM: out = O @ Wo^T + bo (bf16 in, dbuf BK=32) ------

__global__ __launch_bounds__(256) void out_gemm(
    const u16* __restrict__ Ob, const u16* __restrict__ Wob,
    const float* __restrict__ bo, float* __restrict__ out)
{
    __shared__ alignas(16) u16 lA[2][128 * 32];   // 16 KB
    __shared__ alignas(16) u16 lB[2][64 * 32];    // 8 KB

    const int tid = threadIdx.x;
    const int lane = tid & 63, wave = tid >> 6;
    const int wm = wave >> 1, wn = wave & 1;
    const int q = lane >> 4, l15 = lane & 15;
    const int q4 = q * 4;

    const int f = blockIdx.y * 16 + blockIdx.x;
    const int rowbase = (f & 31) * 128;
    const int colbase = (f >> 5) * 64;

    const int srow = wave * 16 + (lane >> 2);
    const int cg = (lane & 3) ^ ((lane >> 2) & 3);
    const u16* gA = Ob  + (size_t)(rowbase + srow) * D_ + cg * 8;
    const u16* gW = Wob + (size_t)(colbase + srow) * D_ + cg * 8;
    const int sdst = wave * 512 + lane * 8;

    const int fo0 = (q ^ (l15 & 3)) * 8;

    f32x4 acc[4][2] = {};

    // prologue: stage k-tile 0 into buf 0 (B: only waves' rows < 64)
    gld16(gA,           &lA[0][sdst]);
    gld16(gA + 64 * D_, &lA[0][2048 + sdst]);
    gld16(gW,           &lB[0][sdst]);

    for (int it = 0; it < 32; ++it) {
        const int buf = it & 1;
        __syncthreads();
        if (it + 1 < 32) {
            const int k1 = (it + 1) * 32;
            gld16(gA + k1,           &lA[buf ^ 1][sdst]);
            gld16(gA + k1 + 64 * D_, &lA[buf ^ 1][2048 + sdst]);
            gld16(gW + k1,           &lB[buf ^ 1][sdst]);
        }
        bf16x8 af[4], bfr[2];
        #pragma unroll
        for (int mi = 0; mi < 4; mi++)
            af[mi] = *(const bf16x8*)&lA[buf][(wm * 64 + mi * 16 + l15) * 32 + fo0];
        #pragma unroll
        for (int ni = 0; ni < 2; ni++)
            bfr[ni] = *(const bf16x8*)&lB[buf][(wn * 32 + ni * 16 + l15) * 32 + fo0];
        #pragma unroll
        for (int mi = 0; mi < 4; mi++)
            #pragma unroll
            for (int ni = 0; ni < 2; ni++)
                acc[mi][ni] = MFMA(af[mi], bfr[ni], acc[mi][ni]);
    }

    #pragma unroll
    for (int mi = 0; mi < 4; mi++)
        #pragma unroll
        for (int ni = 0; ni < 2; ni++) {
            const int c = colbase + wn * 32 + ni * 16 + l15;
            const float bc = bo[c];
            #pragma unroll
            for (int rg = 0; rg < 4; rg++) {
                const int r = rowbase + wm * 64 + mi * 16 + q4 + rg;
                out[(size_t)r * D_ + c] = acc[mi][ni][rg] + bc;
            }
        }
}

// ---------------- launch ----------------

extern "C" void kernel_launch(void* const* d_in, const int* in_sizes, int n_in,
                              void* d_out, int out_size, void* d_ws, size_t ws_size,
                              hipStream_t stream) {
    const float* v  = (const float*)d_in[0];
    const float* k  = (const float*)d_in[1];
    const float* qq = (const float*)d_in[2];
    const float* Wq = (const float*)d_in[3];
    const float* bq = (const float*)d_in[4];
    const float* Wk = (const float*)d_in[5];
    const float* bk = (const float*)d_in[6];
    const float* Wv = (const float*)d_in[7];
    const float* bv = (const float*)d_in[8];
    const float* Wo = (const float*)d_in[9];
    const float* bo = (const float*)d_in[10];
    float* out = (float*)d_out;

    char* w = (char*)d_ws;
    u16* cvtb = (u16*)w;                // 32 MB bf16 arena: vb|kb|qb|Wvb|Wkb|Wqb|Wob
    u16* v2  = (u16*)(w + 33554432);    // 8 MiB (B,H,S,DK), prescaled 0.125*log2e
    u16* k2  = (u16*)(w + 41943040);    // 8 MiB (B,H,S,DK)
    u16* q2T = (u16*)(w + 50331648);    // (B,H,DK,VST) bf16 padded: 8,912,896 B
    u16* Ob  = (u16*)(w + 59244544);    // 8 MiB (B,S,H*DK) bf16

    conv_all<<<16384, 256, 0, stream>>>(v, k, qq, Wv, Wk, Wq, Wo, cvtb);
    proj_gemm<<<dim3(8, 32, 3), 256, 0, stream>>>(cvtb, cvtb + 12582912,
                                                  bv, bk, bq, v2, k2, q2T);
    flash_attn<<<256, 512, 0, stream>>>(v2, k2, q2T, Ob);
    out_gemm<<<dim3(16, 32), 256, 0, stream>>>(Ob, cvtb + 15728640, bo, out);
}

// Round 10
// 212.326 us; speedup vs baseline: 1.0360x; 1.0360x over previous
//
#include <hip/hip_runtime.h>
#include <stdint.h>

#define B_  2
#define S_  2048
#define D_  1024
#define H_  16
#define DK_ 64
#define VST 2176   // q2T padded row stride (4352 B = 17*256): breaks 4KB aliasing

typedef unsigned short u16;
typedef short bf16x8 __attribute__((ext_vector_type(8)));
typedef float f32x4  __attribute__((ext_vector_type(4)));

#define MFMA(a,b,c) __builtin_amdgcn_mfma_f32_16x16x32_bf16((a),(b),(c),0,0,0)
#define EXP2(x) __builtin_amdgcn_exp2f(x)

static __device__ __forceinline__ u16 f2bf(float f) {
    uint32_t u = __float_as_uint(f);
    u += 0x7fffu + ((u >> 16) & 1u);   // RNE
    return (u16)(u >> 16);
}
static __device__ __forceinline__ uint32_t pk2(float x, float y) {
    return __builtin_amdgcn_perm(__float_as_uint(y) + 0x8000u,
                                 __float_as_uint(x) + 0x8000u, 0x07060302u);
}

typedef const __attribute__((address_space(1))) void* gas_p;
typedef __attribute__((address_space(3))) void* las_p;
static __device__ __forceinline__ void gld16(const void* g, void* l) {
    __builtin_amdgcn_global_load_lds((gas_p)g, (las_p)l, 16, 0, 0);
}

// ---------------- one fused f32 -> bf16 conversion pass ----------------
// bf16 arena layout (u16 element offsets):
//   vb 0 | kb 4194304 | qb 8388608 | Wvb 12582912 | Wkb 13631488
//   Wqb 14680064 | Wob 15728640     (total 16M u16 = 32 MB)

__global__ void conv_all(const float* __restrict__ v, const float* __restrict__ k,
                         const float* __restrict__ q,
                         const float* __restrict__ Wv, const float* __restrict__ Wk,
                         const float* __restrict__ Wq, const float* __restrict__ Wo,
                         u16* __restrict__ dst) {
    const int b = blockIdx.x;
    const float* s;
    size_t loc, segbase;
    if (b < 12288) {                          // 3 X tensors, 4096 blocks each
        const int t = b >> 12;
        s = (t == 0) ? v : (t == 1 ? k : q);
        segbase = (size_t)t * 4194304;
        loc = (size_t)(b & 4095) * 1024;
    } else {                                  // 4 W tensors, 1024 blocks each
        const int t = (b - 12288) >> 10;
        s = (t == 0) ? Wv : (t == 1 ? Wk : (t == 2 ? Wq : Wo));
        segbase = 12582912 + (size_t)t * 1048576;
        loc = (size_t)(b & 1023) * 1024;
    }
    loc += threadIdx.x * 4;
    float4 f = *(const float4*)(s + loc);
    ushort4 o;
    o.x = f2bf(f.x); o.y = f2bf(f.y); o.z = f2bf(f.z); o.w = f2bf(f.w);
    *(ushort4*)(dst + segbase + loc) = o;
}

// ---------------- projection GEMMs: C = X @ W^T + bias (bf16, BK=64) ----------
// (verbatim R8 — proven 49 us, conflict-free fragment geometry)

__global__ __launch_bounds__(256) void proj_gemm(
    const u16* __restrict__ Xb, const u16* __restrict__ Wb,
    const float* __restrict__ bv, const float* __restrict__ bk, const float* __restrict__ bq,
    u16* __restrict__ v2, u16* __restrict__ k2, u16* __restrict__ q2T)
{
    __shared__ alignas(16) char smem[40960];   // union: lA(16K)+lB(16K) / epi(40K)
    u16* lA = (u16*)smem;                      // 128 x 64 bf16
    u16* lB = (u16*)(smem + 16384);
    u16* epi = (u16*)smem;                     // [wave][64][80] u16

    const int z = blockIdx.z;
    const u16* A = Xb + (size_t)z * 4194304;   // v / k / q (bf16)
    const u16* W = Wb + (size_t)z * 1048576;   // Wv / Wk / Wq (bf16)
    const float* bias = (z == 0) ? bv : (z == 1 ? bk : bq);

    const int tid = threadIdx.x;
    const int lane = tid & 63, wave = tid >> 6;
    const int wm = wave >> 1, wn = wave & 1;
    const int q = lane >> 4, l15 = lane & 15;
    const int q4 = q * 4;

    const int f = blockIdx.y * 8 + blockIdx.x;
    const int rowbase = (f & 31) * 128;
    const int colbase = (f >> 5) * 128;

    const int srow = wave * 8 + (lane >> 3);
    const int cg = (lane & 7) ^ (lane >> 3);
    const u16* gA = A + (size_t)(rowbase + srow) * D_ + cg * 8;
    const u16* gW = W + (size_t)(colbase + srow) * D_ + cg * 8;
    u16* lAp = lA + wave * 512 + lane * 8;
    u16* lBp = lB + wave * 512 + lane * 8;

    const int sw = l15 & 7;
    const int fo0 = (q ^ sw) * 8;
    const int fo1 = fo0 ^ 32;

    f32x4 acc[4][4] = {};

    for (int k0 = 0; k0 < D_; k0 += 64) {
        #pragma unroll
        for (int j = 0; j < 4; j++) {
            gld16(gA + k0 + (size_t)j * 32 * D_, lAp + j * 2048);
            gld16(gW + k0 + (size_t)j * 32 * D_, lBp + j * 2048);
        }
        __syncthreads();
        bf16x8 a0[4], a1[4], b0[4], b1[4];
        #pragma unroll
        for (int mi = 0; mi < 4; mi++) {
            const int r = (wm * 64 + mi * 16 + l15) * 64;
            a0[mi] = *(const bf16x8*)&lA[r + fo0];
            a1[mi] = *(const bf16x8*)&lA[r + fo1];
        }
        #pragma unroll
        for (int ni = 0; ni < 4; ni++) {
            const int r = (wn * 64 + ni * 16 + l15) * 64;
            b0[ni] = *(const bf16x8*)&lB[r + fo0];
            b1[ni] = *(const bf16x8*)&lB[r + fo1];
        }
        #pragma unroll
        for (int mi = 0; mi < 4; mi++)
            #pragma unroll
            for (int ni = 0; ni < 4; ni++) {
                acc[mi][ni] = MFMA(a0[mi], b0[ni], acc[mi][ni]);
                acc[mi][ni] = MFMA(a1[mi], b1[ni], acc[mi][ni]);
            }
        __syncthreads();
    }

    u16* ep = epi + wave * (64 * 80);
    const int h = (colbase + wn * 64) >> 6;
    const int Mrow0 = rowbase + wm * 64;
    const int bb = Mrow0 >> 11;

    if (z < 2) {
        u16* outp = (z == 0) ? v2 : k2;
        const float scale = (z == 0) ? 0.18033688011112042f : 1.0f;  // 0.125*log2(e)
        #pragma unroll
        for (int mi = 0; mi < 4; mi++)
            #pragma unroll
            for (int ni = 0; ni < 4; ni++) {
                const float bc = bias[colbase + wn * 64 + ni * 16 + l15];
                #pragma unroll
                for (int rg = 0; rg < 4; rg++)
                    ep[(mi * 16 + q4 + rg) * 80 + ni * 16 + l15] =
                        f2bf((acc[mi][ni][rg] + bc) * scale);
            }
        asm volatile("s_waitcnt lgkmcnt(0)" ::: "memory");
        const int s = (Mrow0 + lane) & (S_ - 1);
        u16* gb = outp + ((size_t)(bb * H_ + h) * S_ + s) * DK_;
        #pragma unroll
        for (int j = 0; j < 8; j++)
            *(uint4*)(gb + j * 8) = *(const uint4*)&ep[lane * 80 + j * 8];
    } else {
        #pragma unroll
        for (int mi = 0; mi < 4; mi++)
            #pragma unroll
            for (int ni = 0; ni < 4; ni++) {
                const float bc = bias[colbase + wn * 64 + ni * 16 + l15];
                uint2 pk;
                pk.x = pk2(acc[mi][ni][0] + bc, acc[mi][ni][1] + bc);
                pk.y = pk2(acc[mi][ni][2] + bc, acc[mi][ni][3] + bc);
                *(uint2*)&ep[(ni * 16 + l15) * 80 + mi * 16 + q4] = pk;
            }
        asm volatile("s_waitcnt lgkmcnt(0)" ::: "memory");
        const int s0g = Mrow0 & (S_ - 1);
        u16* gb = q2T + ((size_t)(bb * H_ + h) * DK_ + lane) * VST + s0g;
        #pragma unroll
        for (int j = 0; j < 8; j++)
            *(uint4*)(gb + j * 8) = *(const uint4*)&ep[lane * 80 + j * 8];
    }
}

// ---------------- flash attention v5: g=4 t-split + LDS <= 80 KiB ------------
// R8 structure with ldsP pad-68 replaced by stride-64 + column XOR swizzle
// (col ^ (l15&7)*8): banks 4(q^(l15&7)) -> max 2-way aliasing (free), and
// total LDS drops 82944 -> 81920 so 2 blocks/CU (16 waves) can reside.

__global__ __launch_bounds__(512, 2) void flash_attn(
    const u16* __restrict__ v2, const u16* __restrict__ k2,
    const u16* __restrict__ q2T, u16* __restrict__ Ob)
{
    __shared__ alignas(16) char smem[81920];
    u16* lK   = (u16*)smem;                  // [th 2][buf 2][64*64]
    u16* lV   = (u16*)(smem + 32768);        // [th 2][buf 2][64*64]
    u16* ldsP = (u16*)(smem + 65536);        // [wave 8][16][64] XOR-swizzled
    float* Xo = (float*)smem;                // epilogue overlay: [wl 4][64][68] f32
    float* Xl = (float*)(smem + 69632);      // [256] f32

    const int tid = threadIdx.x;
    const int lane = tid & 63, wave = tid >> 6;
    const int th = wave >> 2, wl = wave & 3;
    const int q = lane >> 4, l15 = lane & 15;
    const int q4 = q * 4;
    const int bh = blockIdx.x & 31;
    const int sbase = (blockIdx.x >> 5) * 256;
    const int tbase = th * 1024;

    const u16* Qp = v2  + (size_t)bh * S_ * DK_;
    const u16* Kp = k2  + (size_t)bh * S_ * DK_;
    const u16* Vp = q2T + (size_t)bh * DK_ * VST;

    const int srow8 = lane >> 3;
    const int cs    = lane & 7;
    const int cg    = cs ^ srow8;
    const int krow0 = wl * 16 + srow8;
    u16* lKh = lK + th * 8192;
    u16* lVh = lV + th * 8192;

    bf16x8 bq[4][2];
    #pragma unroll
    for (int g = 0; g < 4; g++) {
        const u16* qp = Qp + (size_t)(sbase + wl * 64 + g * 16 + l15) * DK_ + q * 8;
        bq[g][0] = *(const bf16x8*)(qp);
        bq[g][1] = *(const bf16x8*)(qp + 32);
    }

    bf16x8 ones;
    #pragma unroll
    for (int i = 0; i < 8; i++) ones[i] = (short)0x3F80;

    f32x4 o_acc[4][4] = {};
    f32x4 o_l[4] = {};

    const int sw = l15 & 7;
    const int fc0 = (q ^ sw) * 8;
    const int fc1 = fc0 ^ 32;
    const int fp = sw * 8;                   // ldsP column XOR (8-aligned)

    {
        const u16* kg = Kp + (size_t)(tbase + krow0) * DK_ + cg * 8;
        const u16* vg = Vp + (size_t)krow0 * VST + tbase + cg * 8;
        u16* lkd = lKh + wl * 1024 + lane * 8;
        u16* lvd = lVh + wl * 1024 + lane * 8;
        gld16(kg, lkd);
        gld16(kg + 8 * DK_, lkd + 512);
        gld16(vg, lvd);
        gld16(vg + (size_t)8 * VST, lvd + 512);
    }

    u16* Pw = ldsP + wave * 1024;            // [16][64] swizzled

    for (int it = 0; it < 16; ++it) {
        const int buf = it & 1;
        __syncthreads();
        if (it + 1 < 16) {
            const int t1 = tbase + (it + 1) * 64;
            const u16* kg = Kp + (size_t)(t1 + krow0) * DK_ + cg * 8;
            const u16* vg = Vp + (size_t)krow0 * VST + t1 + cg * 8;
            u16* lkd = lKh + (buf ^ 1) * 4096 + wl * 1024 + lane * 8;
            u16* lvd = lVh + (buf ^ 1) * 4096 + wl * 1024 + lane * 8;
            gld16(kg, lkd);
            gld16(kg + 8 * DK_, lkd + 512);
            gld16(vg, lvd);
            gld16(vg + (size_t)8 * VST, lvd + 512);
        }

        const u16* Kt = lKh + buf * 4096;
        const u16* Vt = lVh + buf * 4096;
        bf16x8 ak0[4], ak1[4], av0[4], av1[4];
        #pragma unroll
        for (int mi = 0; mi < 4; mi++) {
            const int r = (mi * 16 + l15) * 64;
            ak0[mi] = *(const bf16x8*)&Kt[r + fc0];
            ak1[mi] = *(const bf16x8*)&Kt[r + fc1];
            av0[mi] = *(const bf16x8*)&Vt[r + fc0];
            av1[mi] = *(const bf16x8*)&Vt[r + fc1];
        }

        #pragma unroll
        for (int g = 0; g < 4; g++) {
            f32x4 sa[4];
            #pragma unroll
            for (int mi = 0; mi < 4; mi++) {
                f32x4 zz = {};
                zz = MFMA(ak0[mi], bq[g][0], zz);
                sa[mi] = MFMA(ak1[mi], bq[g][1], zz);
            }
            #pragma unroll
            for (int mi = 0; mi < 4; mi++) {
                float p0 = EXP2(sa[mi][0]);
                float p1 = EXP2(sa[mi][1]);
                float p2 = EXP2(sa[mi][2]);
                float p3 = EXP2(sa[mi][3]);
                uint2 pk;
                pk.x = __builtin_amdgcn_perm(__float_as_uint(p1), __float_as_uint(p0), 0x07060302u);
                pk.y = __builtin_amdgcn_perm(__float_as_uint(p3), __float_as_uint(p2), 0x07060302u);
                *(uint2*)&Pw[l15 * 64 + ((mi * 16 + q4) ^ fp)] = pk;
            }
            asm volatile("s_waitcnt lgkmcnt(0)" ::: "memory");
            bf16x8 bp0, bp1;
            {
                const int b0o = l15 * 64 + ((q * 8) ^ fp);
                const int b1o = l15 * 64 + ((32 + q * 8) ^ fp);
                uint2* r0 = (uint2*)&bp0;
                r0[0] = *(const uint2*)&Pw[b0o];
                r0[1] = *(const uint2*)&Pw[b0o + 4];
                uint2* r1 = (uint2*)&bp1;
                r1[0] = *(const uint2*)&Pw[b1o];
                r1[1] = *(const uint2*)&Pw[b1o + 4];
            }
            #pragma unroll
            for (int mi = 0; mi < 4; mi++) {
                o_acc[g][mi] = MFMA(av0[mi], bp0, o_acc[g][mi]);
                o_acc[g][mi] = MFMA(av1[mi], bp1, o_acc[g][mi]);
            }
            o_l[g] = MFMA(ones, bp0, o_l[g]);
            o_l[g] = MFMA(ones, bp1, o_l[g]);
        }
    }

    __syncthreads();
    if (th == 1) {
        #pragma unroll
        for (int g = 0; g < 4; g++) {
            const int sr = wl * 64 + g * 16 + l15;
            #pragma unroll
            for (int mi = 0; mi < 4; mi++)
                *(f32x4*)&Xo[sr * 68 + mi * 16 + q4] = o_acc[g][mi];
            if (q == 0) Xl[sr] = o_l[g][0];
        }
    }
    __syncthreads();
    if (th == 0) {
        const int bb = bh >> 4, h = bh & 15;
        #pragma unroll
        for (int g = 0; g < 4; g++) {
            const int sr = wl * 64 + g * 16 + l15;
            const float inv_l = 1.0f / (o_l[g][0] + Xl[sr]);
            const int s = sbase + sr;
            #pragma unroll
            for (int mi = 0; mi < 4; mi++) {
                f32x4 p = *(const f32x4*)&Xo[sr * 68 + mi * 16 + q4];
                ushort4 o4;
                o4.x = f2bf((o_acc[g][mi][0] + p[0]) * inv_l);
                o4.y = f2bf((o_acc[g][mi][1] + p[1]) * inv_l);
                o4.z = f2bf((o_acc[g][mi][2] + p[2]) * inv_l);
                o4.w = f2bf((o_acc[g][mi][3] + p[3]) * inv_l);
                *(ushort4*)(Ob + (size_t)(bb * S_ + s) * (H_ * DK_) + h * DK_ + mi * 16 + q4) = o4;
            }
        }
    }
}

// ---------------- output GEMM: out = O @ Wo^T + bo (bf16 in, BK=64) ----------
// (verbatim R8)

__global__ __launch_bounds__(256) void out_gemm(
    const u16* __restrict__ Ob, const u16* __restrict__ Wob,
    const float* __restrict__ bo, float* __restrict__ out)
{
    __shared__ alignas(16) u16 lA[128 * 64];   // 16 KB
    __shared__ alignas(16) u16 lB[64 * 64];    // 8 KB

    const int tid = threadIdx.x;
    const int lane = tid & 63, wave = tid >> 6;
    const int wm = wave >> 1, wn = wave & 1;
    const int q = lane >> 4, l15 = lane & 15;
    const int q4 = q * 4;

    const int f = blockIdx.y * 16 + blockIdx.x;
    const int rowbase = (f & 31) * 128;
    const int colbase = (f >> 5) * 64;

    const int srow = wave * 8 + (lane >> 3);
    const int cg = (lane & 7) ^ (lane >> 3);
    const u16* gA = Ob  + (size_t)(rowbase + srow) * D_ + cg * 8;
    const u16* gW = Wob + (size_t)(colbase + srow) * D_ + cg * 8;
    u16* lAp = lA + wave * 512 + lane * 8;
    u16* lBp = lB + wave * 512 + lane * 8;

    const int sw = l15 & 7;
    const int fo0 = (q ^ sw) * 8;
    const int fo1 = fo0 ^ 32;

    f32x4 acc[4][2] = {};

    for (int k0 = 0; k0 < D_; k0 += 64) {
        #pragma unroll
        for (int j = 0; j < 4; j++)
            gld16(gA + k0 + (size_t)j * 32 * D_, lAp + j * 2048);
        #pragma unroll
        for (int j = 0; j < 2; j++)
            gld16(gW + k0 + (size_t)j * 32 * D_, lBp + j * 2048);
        __syncthreads();
        bf16x8 a0[4], a1[4], b0[2], b1[2];
        #pragma unroll
        for (int mi = 0; mi < 4; mi++) {
            const int r = (wm * 64 + mi * 16 + l15) * 64;
            a0[mi] = *(const bf16x8*)&lA[r + fo0];
            a1[mi] = *(const bf16x8*)&lA[r + fo1];
        }
        #pragma unroll
        for (int ni = 0; ni < 2; ni++) {
            const int r = (wn * 32 + ni * 16 + l15) * 64;
            b0[ni] = *(const bf16x8*)&lB[r + fo0];
            b1[ni] = *(const bf16x8*)&lB[r + fo1];
        }
        #pragma unroll
        for (int mi = 0; mi < 4; mi++)
            #pragma unroll
            for (int ni = 0; ni < 2; ni++) {
                acc[mi][ni] = MFMA(a0[mi], b0[ni], acc[mi][ni]);
                acc[mi][ni] = MFMA(a1[mi], b1[ni], acc[mi][ni]);
            }
        __syncthreads();
    }

    #pragma unroll
    for (int mi = 0; mi < 4; mi++)
        #pragma unroll
        for (int ni = 0; ni < 2; ni++) {
            const int c = colbase + wn * 32 + ni * 16 + l15;
            const float bc = bo[c];
            #pragma unroll
            for (int rg = 0; rg < 4; rg++) {
                const int r = rowbase + wm * 64 + mi * 16 + q4 + rg;
                out[(size_t)r * D_ + c] = acc[mi][ni][rg] + bc;
            }
        }
}

// ---------------- launch ----------------

extern "C" void kernel_launch(void* const* d_in, const int* in_sizes, int n_in,
                              void* d_out, int out_size, void* d_ws, size_t ws_size,
                              hipStream_t stream) {
    const float* v  = (const float*)d_in[0];
    const float* k  = (const float*)d_in[1];
    const float* qq = (const float*)d_in[2];
    const float* Wq = (const float*)d_in[3];
    const float* bq = (const float*)d_in[4];
    const float* Wk = (const float*)d_in[5];
    const float* bk = (const float*)d_in[6];
    const float* Wv = (const float*)d_in[7];
    const float* bv = (const float*)d_in[8];
    const float* Wo = (const float*)d_in[9];
    const float* bo = (const float*)d_in[10];
    float* out = (float*)d_out;

    char* w = (char*)d_ws;
    u16* cvtb = (u16*)w;                // 32 MB bf16 arena: vb|kb|qb|Wvb|Wkb|Wqb|Wob
    u16* v2  = (u16*)(w + 33554432);    // 8 MiB (B,H,S,DK), prescaled 0.125*log2e
    u16* k2  = (u16*)(w + 41943040);    // 8 MiB (B,H,S,DK)
    u16* q2T = (u16*)(w + 50331648);    // (B,H,DK,VST) bf16 padded: 8,912,896 B
    u16* Ob  = (u16*)(w + 59244544);    // 8 MiB (B,S,H*DK) bf16

    conv_all<<<16384, 256, 0, stream>>>(v, k, qq, Wv, Wk, Wq, Wo, cvtb);
    proj_gemm<<<dim3(8, 32, 3), 256, 0, stream>>>(cvtb, cvtb + 12582912,
                                                  bv, bk, bq, v2, k2, q2T);
    flash_attn<<<256, 512, 0, stream>>>(v2, k2, q2T, Ob);
    out_gemm<<<dim3(16, 32), 256, 0, stream>>>(Ob, cvtb + 15728640, bo, out);
}

// Round 11
// 210.777 us; speedup vs baseline: 1.0436x; 1.0073x over previous
//
#include <hip/hip_runtime.h>
#include <stdint.h>

#define B_  2
#define S_  2048
#define D_  1024
#define H_  16
#define DK_ 64
#define VST 2176   // q2T padded row stride (4352 B = 17*256): breaks 4KB aliasing

typedef unsigned short u16;
typedef short bf16x8 __attribute__((ext_vector_type(8)));
typedef float f32x4  __attribute__((ext_vector_type(4)));

#define MFMA(a,b,c) __builtin_amdgcn_mfma_f32_16x16x32_bf16((a),(b),(c),0,0,0)
#define EXP2(x) __builtin_amdgcn_exp2f(x)

static __device__ __forceinline__ u16 f2bf(float f) {
    uint32_t u = __float_as_uint(f);
    u += 0x7fffu + ((u >> 16) & 1u);   // RNE
    return (u16)(u >> 16);
}
static __device__ __forceinline__ uint32_t pk2(float x, float y) {
    return __builtin_amdgcn_perm(__float_as_uint(y) + 0x8000u,
                                 __float_as_uint(x) + 0x8000u, 0x07060302u);
}

typedef const __attribute__((address_space(1))) void* gas_p;
typedef __attribute__((address_space(3))) void* las_p;
static __device__ __forceinline__ void gld16(const void* g, void* l) {
    __builtin_amdgcn_global_load_lds((gas_p)g, (las_p)l, 16, 0, 0);
}

// ---------------- one fused f32 -> bf16 conversion pass ----------------
// bf16 arena layout (u16 element offsets):
//   vb 0 | kb 4194304 | qb 8388608 | Wvb 12582912 | Wkb 13631488
//   Wqb 14680064 | Wob 15728640     (total 16M u16 = 32 MB)

__global__ void conv_all(const float* __restrict__ v, const float* __restrict__ k,
                         const float* __restrict__ q,
                         const float* __restrict__ Wv, const float* __restrict__ Wk,
                         const float* __restrict__ Wq, const float* __restrict__ Wo,
                         u16* __restrict__ dst) {
    const int b = blockIdx.x;
    const float* s;
    size_t loc, segbase;
    if (b < 12288) {                          // 3 X tensors, 4096 blocks each
        const int t = b >> 12;
        s = (t == 0) ? v : (t == 1 ? k : q);
        segbase = (size_t)t * 4194304;
        loc = (size_t)(b & 4095) * 1024;
    } else {                                  // 4 W tensors, 1024 blocks each
        const int t = (b - 12288) >> 10;
        s = (t == 0) ? Wv : (t == 1 ? Wk : (t == 2 ? Wq : Wo));
        segbase = 12582912 + (size_t)t * 1048576;
        loc = (size_t)(b & 1023) * 1024;
    }
    loc += threadIdx.x * 4;
    float4 f = *(const float4*)(s + loc);
    ushort4 o;
    o.x = f2bf(f.x); o.y = f2bf(f.y); o.z = f2bf(f.z); o.w = f2bf(f.w);
    *(ushort4*)(dst + segbase + loc) = o;
}

// ---------------- projection GEMMs: C = X @ W^T + bias (bf16, BK=64) ----------
// (verbatim R8/R10 — proven 47 us, conflict-free fragment geometry)

__global__ __launch_bounds__(256) void proj_gemm(
    const u16* __restrict__ Xb, const u16* __restrict__ Wb,
    const float* __restrict__ bv, const float* __restrict__ bk, const float* __restrict__ bq,
    u16* __restrict__ v2, u16* __restrict__ k2, u16* __restrict__ q2T)
{
    __shared__ alignas(16) char smem[40960];   // union: lA(16K)+lB(16K) / epi(40K)
    u16* lA = (u16*)smem;                      // 128 x 64 bf16
    u16* lB = (u16*)(smem + 16384);
    u16* epi = (u16*)smem;                     // [wave][64][80] u16

    const int z = blockIdx.z;
    const u16* A = Xb + (size_t)z * 4194304;   // v / k / q (bf16)
    const u16* W = Wb + (size_t)z * 1048576;   // Wv / Wk / Wq (bf16)
    const float* bias = (z == 0) ? bv : (z == 1 ? bk : bq);

    const int tid = threadIdx.x;
    const int lane = tid & 63, wave = tid >> 6;
    const int wm = wave >> 1, wn = wave & 1;
    const int q = lane >> 4, l15 = lane & 15;
    const int q4 = q * 4;

    const int f = blockIdx.y * 8 + blockIdx.x;
    const int rowbase = (f & 31) * 128;
    const int colbase = (f >> 5) * 128;

    const int srow = wave * 8 + (lane >> 3);
    const int cg = (lane & 7) ^ (lane >> 3);
    const u16* gA = A + (size_t)(rowbase + srow) * D_ + cg * 8;
    const u16* gW = W + (size_t)(colbase + srow) * D_ + cg * 8;
    u16* lAp = lA + wave * 512 + lane * 8;
    u16* lBp = lB + wave * 512 + lane * 8;

    const int sw = l15 & 7;
    const int fo0 = (q ^ sw) * 8;
    const int fo1 = fo0 ^ 32;

    f32x4 acc[4][4] = {};

    for (int k0 = 0; k0 < D_; k0 += 64) {
        #pragma unroll
        for (int j = 0; j < 4; j++) {
            gld16(gA + k0 + (size_t)j * 32 * D_, lAp + j * 2048);
            gld16(gW + k0 + (size_t)j * 32 * D_, lBp + j * 2048);
        }
        __syncthreads();
        bf16x8 a0[4], a1[4], b0[4], b1[4];
        #pragma unroll
        for (int mi = 0; mi < 4; mi++) {
            const int r = (wm * 64 + mi * 16 + l15) * 64;
            a0[mi] = *(const bf16x8*)&lA[r + fo0];
            a1[mi] = *(const bf16x8*)&lA[r + fo1];
        }
        #pragma unroll
        for (int ni = 0; ni < 4; ni++) {
            const int r = (wn * 64 + ni * 16 + l15) * 64;
            b0[ni] = *(const bf16x8*)&lB[r + fo0];
            b1[ni] = *(const bf16x8*)&lB[r + fo1];
        }
        #pragma unroll
        for (int mi = 0; mi < 4; mi++)
            #pragma unroll
            for (int ni = 0; ni < 4; ni++) {
                acc[mi][ni] = MFMA(a0[mi], b0[ni], acc[mi][ni]);
                acc[mi][ni] = MFMA(a1[mi], b1[ni], acc[mi][ni]);
            }
        __syncthreads();
    }

    u16* ep = epi + wave * (64 * 80);
    const int h = (colbase + wn * 64) >> 6;
    const int Mrow0 = rowbase + wm * 64;
    const int bb = Mrow0 >> 11;

    if (z < 2) {
        u16* outp = (z == 0) ? v2 : k2;
        const float scale = (z == 0) ? 0.18033688011112042f : 1.0f;  // 0.125*log2(e)
        #pragma unroll
        for (int mi = 0; mi < 4; mi++)
            #pragma unroll
            for (int ni = 0; ni < 4; ni++) {
                const float bc = bias[colbase + wn * 64 + ni * 16 + l15];
                #pragma unroll
                for (int rg = 0; rg < 4; rg++)
                    ep[(mi * 16 + q4 + rg) * 80 + ni * 16 + l15] =
                        f2bf((acc[mi][ni][rg] + bc) * scale);
            }
        asm volatile("s_waitcnt lgkmcnt(0)" ::: "memory");
        const int s = (Mrow0 + lane) & (S_ - 1);
        u16* gb = outp + ((size_t)(bb * H_ + h) * S_ + s) * DK_;
        #pragma unroll
        for (int j = 0; j < 8; j++)
            *(uint4*)(gb + j * 8) = *(const uint4*)&ep[lane * 80 + j * 8];
    } else {
        #pragma unroll
        for (int mi = 0; mi < 4; mi++)
            #pragma unroll
            for (int ni = 0; ni < 4; ni++) {
                const float bc = bias[colbase + wn * 64 + ni * 16 + l15];
                uint2 pk;
                pk.x = pk2(acc[mi][ni][0] + bc, acc[mi][ni][1] + bc);
                pk.y = pk2(acc[mi][ni][2] + bc, acc[mi][ni][3] + bc);
                *(uint2*)&ep[(ni * 16 + l15) * 80 + mi * 16 + q4] = pk;
            }
        asm volatile("s_waitcnt lgkmcnt(0)" ::: "memory");
        const int s0g = Mrow0 & (S_ - 1);
        u16* gb = q2T + ((size_t)(bb * H_ + h) * DK_ + lane) * VST + s0g;
        #pragma unroll
        for (int j = 0; j < 8; j++)
            *(uint4*)(gb + j * 8) = *(const uint4*)&ep[lane * 80 + j * 8];
    }
}

// ---------------- flash attention v5 (verbatim R10) ----------------
// Roles (source bug): "query"=v2 (prescaled, log2 domain), "key"=k2, "value"=q2.

__global__ __launch_bounds__(512, 2) void flash_attn(
    const u16* __restrict__ v2, const u16* __restrict__ k2,
    const u16* __restrict__ q2T, u16* __restrict__ Ob)
{
    __shared__ alignas(16) char smem[81920];
    u16* lK   = (u16*)smem;                  // [th 2][buf 2][64*64]
    u16* lV   = (u16*)(smem + 32768);        // [th 2][buf 2][64*64]
    u16* ldsP = (u16*)(smem + 65536);        // [wave 8][16][64] XOR-swizzled
    float* Xo = (float*)smem;                // epilogue overlay: [wl 4][64][68] f32
    float* Xl = (float*)(smem + 69632);      // [256] f32

    const int tid = threadIdx.x;
    const int lane = tid & 63, wave = tid >> 6;
    const int th = wave >> 2, wl = wave & 3;
    const int q = lane >> 4, l15 = lane & 15;
    const int q4 = q * 4;
    const int bh = blockIdx.x & 31;
    const int sbase = (blockIdx.x >> 5) * 256;
    const int tbase = th * 1024;

    const u16* Qp = v2  + (size_t)bh * S_ * DK_;
    const u16* Kp = k2  + (size_t)bh * S_ * DK_;
    const u16* Vp = q2T + (size_t)bh * DK_ * VST;

    const int srow8 = lane >> 3;
    const int cs    = lane & 7;
    const int cg    = cs ^ srow8;
    const int krow0 = wl * 16 + srow8;
    u16* lKh = lK + th * 8192;
    u16* lVh = lV + th * 8192;

    bf16x8 bq[4][2];
    #pragma unroll
    for (int g = 0; g < 4; g++) {
        const u16* qp = Qp + (size_t)(sbase + wl * 64 + g * 16 + l15) * DK_ + q * 8;
        bq[g][0] = *(const bf16x8*)(qp);
        bq[g][1] = *(const bf16x8*)(qp + 32);
    }

    bf16x8 ones;
    #pragma unroll
    for (int i = 0; i < 8; i++) ones[i] = (short)0x3F80;

    f32x4 o_acc[4][4] = {};
    f32x4 o_l[4] = {};

    const int sw = l15 & 7;
    const int fc0 = (q ^ sw) * 8;
    const int fc1 = fc0 ^ 32;
    const int fp = sw * 8;                   // ldsP column XOR (8-aligned)

    {
        const u16* kg = Kp + (size_t)(tbase + krow0) * DK_ + cg * 8;
        const u16* vg = Vp + (size_t)krow0 * VST + tbase + cg * 8;
        u16* lkd = lKh + wl * 1024 + lane * 8;
        u16* lvd = lVh + wl * 1024 + lane * 8;
        gld16(kg, lkd);
        gld16(kg + 8 * DK_, lkd + 512);
        gld16(vg, lvd);
        gld16(vg + (size_t)8 * VST, lvd + 512);
    }

    u16* Pw = ldsP + wave * 1024;            // [16][64] swizzled

    for (int it = 0; it < 16; ++it) {
        const int buf = it & 1;
        __syncthreads();
        if (it + 1 < 16) {
            const int t1 = tbase + (it + 1) * 64;
            const u16* kg = Kp + (size_t)(t1 + krow0) * DK_ + cg * 8;
            const u16* vg = Vp + (size_t)krow0 * VST + t1 + cg * 8;
            u16* lkd = lKh + (buf ^ 1) * 4096 + wl * 1024 + lane * 8;
            u16* lvd = lVh + (buf ^ 1) * 4096 + wl * 1024 + lane * 8;
            gld16(kg, lkd);
            gld16(kg + 8 * DK_, lkd + 512);
            gld16(vg, lvd);
            gld16(vg + (size_t)8 * VST, lvd + 512);
        }

        const u16* Kt = lKh + buf * 4096;
        const u16* Vt = lVh + buf * 4096;
        bf16x8 ak0[4], ak1[4], av0[4], av1[4];
        #pragma unroll
        for (int mi = 0; mi < 4; mi++) {
            const int r = (mi * 16 + l15) * 64;
            ak0[mi] = *(const bf16x8*)&Kt[r + fc0];
            ak1[mi] = *(const bf16x8*)&Kt[r + fc1];
            av0[mi] = *(const bf16x8*)&Vt[r + fc0];
            av1[mi] = *(const bf16x8*)&Vt[r + fc1];
        }

        #pragma unroll
        for (int g = 0; g < 4; g++) {
            f32x4 sa[4];
            #pragma unroll
            for (int mi = 0; mi < 4; mi++) {
                f32x4 zz = {};
                zz = MFMA(ak0[mi], bq[g][0], zz);
                sa[mi] = MFMA(ak1[mi], bq[g][1], zz);
            }
            #pragma unroll
            for (int mi = 0; mi < 4; mi++) {
                float p0 = EXP2(sa[mi][0]);
                float p1 = EXP2(sa[mi][1]);
                float p2 = EXP2(sa[mi][2]);
                float p3 = EXP2(sa[mi][3]);
                uint2 pk;
                pk.x = __builtin_amdgcn_perm(__float_as_uint(p1), __float_as_uint(p0), 0x07060302u);
                pk.y = __builtin_amdgcn_perm(__float_as_uint(p3), __float_as_uint(p2), 0x07060302u);
                *(uint2*)&Pw[l15 * 64 + ((mi * 16 + q4) ^ fp)] = pk;
            }
            asm volatile("s_waitcnt lgkmcnt(0)" ::: "memory");
            bf16x8 bp0, bp1;
            {
                const int b0o = l15 * 64 + ((q * 8) ^ fp);
                const int b1o = l15 * 64 + ((32 + q * 8) ^ fp);
                uint2* r0 = (uint2*)&bp0;
                r0[0] = *(const uint2*)&Pw[b0o];
                r0[1] = *(const uint2*)&Pw[b0o + 4];
                uint2* r1 = (uint2*)&bp1;
                r1[0] = *(const uint2*)&Pw[b1o];
                r1[1] = *(const uint2*)&Pw[b1o + 4];
            }
            #pragma unroll
            for (int mi = 0; mi < 4; mi++) {
                o_acc[g][mi] = MFMA(av0[mi], bp0, o_acc[g][mi]);
                o_acc[g][mi] = MFMA(av1[mi], bp1, o_acc[g][mi]);
            }
            o_l[g] = MFMA(ones, bp0, o_l[g]);
            o_l[g] = MFMA(ones, bp1, o_l[g]);
        }
    }

    __syncthreads();
    if (th == 1) {
        #pragma unroll
        for (int g = 0; g < 4; g++) {
            const int sr = wl * 64 + g * 16 + l15;
            #pragma unroll
            for (int mi = 0; mi < 4; mi++)
                *(f32x4*)&Xo[sr * 68 + mi * 16 + q4] = o_acc[g][mi];
            if (q == 0) Xl[sr] = o_l[g][0];
        }
    }
    __syncthreads();
    if (th == 0) {
        const int bb = bh >> 4, h = bh & 15;
        #pragma unroll
        for (int g = 0; g < 4; g++) {
            const int sr = wl * 64 + g * 16 + l15;
            const float inv_l = 1.0f / (o_l[g][0] + Xl[sr]);
            const int s = sbase + sr;
            #pragma unroll
            for (int mi = 0; mi < 4; mi++) {
                f32x4 p = *(const f32x4*)&Xo[sr * 68 + mi * 16 + q4];
                ushort4 o4;
                o4.x = f2bf((o_acc[g][mi][0] + p[0]) * inv_l);
                o4.y = f2bf((o_acc[g][mi][1] + p[1]) * inv_l);
                o4.z = f2bf((o_acc[g][mi][2] + p[2]) * inv_l);
                o4.w = f2bf((o_acc[g][mi][3] + p[3]) * inv_l);
                *(ushort4*)(Ob + (size_t)(bb * S_ + s) * (H_ * DK_) + h * DK_ + mi * 16 + q4) = o4;
            }
        }
    }
}

// ---------------- output GEMM: out = O @ Wo^T + bo (bf16 in, BK=128) ----------
// BK=128 stored as two 64-col half-tiles, each with the R8-proven 8-chunk XOR
// geometry (identical bank behavior). Barriers halve: 16 iters -> 8.

__global__ __launch_bounds__(256) void out_gemm(
    const u16* __restrict__ Ob, const u16* __restrict__ Wob,
    const float* __restrict__ bo, float* __restrict__ out)
{
    __shared__ alignas(16) u16 lA[2][128 * 64];   // [k-half][row][64] = 32 KB
    __shared__ alignas(16) u16 lB[2][64 * 64];    // 16 KB

    const int tid = threadIdx.x;
    const int lane = tid & 63, wave = tid >> 6;
    const int wm = wave >> 1, wn = wave & 1;
    const int q = lane >> 4, l15 = lane & 15;
    const int q4 = q * 4;

    const int f = blockIdx.y * 16 + blockIdx.x;
    const int rowbase = (f & 31) * 128;
    const int colbase = (f >> 5) * 64;

    const int srow = wave * 8 + (lane >> 3);
    const int cg = (lane & 7) ^ (lane >> 3);
    const u16* gA = Ob  + (size_t)(rowbase + srow) * D_ + cg * 8;
    const u16* gW = Wob + (size_t)(colbase + srow) * D_ + cg * 8;
    const int sdst = wave * 512 + lane * 8;

    const int sw = l15 & 7;
    const int fo0 = (q ^ sw) * 8;
    const int fo1 = fo0 ^ 32;

    f32x4 acc[4][2] = {};

    for (int k0 = 0; k0 < D_; k0 += 128) {
        #pragma unroll
        for (int j = 0; j < 4; j++) {
            gld16(gA + k0 + (size_t)j * 32 * D_,      &lA[0][j * 2048 + sdst]);
            gld16(gA + k0 + 64 + (size_t)j * 32 * D_, &lA[1][j * 2048 + sdst]);
        }
        #pragma unroll
        for (int j = 0; j < 2; j++) {
            gld16(gW + k0 + (size_t)j * 32 * D_,      &lB[0][j * 2048 + sdst]);
            gld16(gW + k0 + 64 + (size_t)j * 32 * D_, &lB[1][j * 2048 + sdst]);
        }
        __syncthreads();
        #pragma unroll
        for (int h = 0; h < 2; h++) {
            bf16x8 a0[4], a1[4], b0[2], b1[2];
            #pragma unroll
            for (int mi = 0; mi < 4; mi++) {
                const int r = (wm * 64 + mi * 16 + l15) * 64;
                a0[mi] = *(const bf16x8*)&lA[h][r + fo0];
                a1[mi] = *(const bf16x8*)&lA[h][r + fo1];
            }
            #pragma unroll
            for (int ni = 0; ni < 2; ni++) {
                const int r = (wn * 32 + ni * 16 + l15) * 64;
                b0[ni] = *(const bf16x8*)&lB[h][r + fo0];
                b1[ni] = *(const bf16x8*)&lB[h][r + fo1];
            }
            #pragma unroll
            for (int mi = 0; mi < 4; mi++)
                #pragma unroll
                for (int ni = 0; ni < 2; ni++) {
                    acc[mi][ni] = MFMA(a0[mi], b0[ni], acc[mi][ni]);
                    acc[mi][ni] = MFMA(a1[mi], b1[ni], acc[mi][ni]);
                }
        }
        __syncthreads();
    }

    #pragma unroll
    for (int mi = 0; mi < 4; mi++)
        #pragma unroll
        for (int ni = 0; ni < 2; ni++) {
            const int c = colbase + wn * 32 + ni * 16 + l15;
            const float bc = bo[c];
            #pragma unroll
            for (int rg = 0; rg < 4; rg++) {
                const int r = rowbase + wm * 64 + mi * 16 + q4 + rg;
                out[(size_t)r * D_ + c] = acc[mi][ni][rg] + bc;
            }
        }
}

// ---------------- launch ----------------

extern "C" void kernel_launch(void* const* d_in, const int* in_sizes, int n_in,
                              void* d_out, int out_size, void* d_ws, size_t ws_size,
                              hipStream_t stream) {
    const float* v  = (const float*)d_in[0];
    const float* k  = (const float*)d_in[1];
    const float* qq = (const float*)d_in[2];
    const float* Wq = (const float*)d_in[3];
    const float* bq = (const float*)d_in[4];
    const float* Wk = (const float*)d_in[5];
    const float* bk = (const float*)d_in[6];
    const float* Wv = (const float*)d_in[7];
    const float* bv = (const float*)d_in[8];
    const float* Wo = (const float*)d_in[9];
    const float* bo = (const float*)d_in[10];
    float* out = (float*)d_out;

    char* w = (char*)d_ws;
    u16* cvtb = (u16*)w;                // 32 MB bf16 arena: vb|kb|qb|Wvb|Wkb|Wqb|Wob
    u16* v2  = (u16*)(w + 33554432);    // 8 MiB (B,H,S,DK), prescaled 0.125*log2e
    u16* k2  = (u16*)(w + 41943040);    // 8 MiB (B,H,S,DK)
    u16* q2T = (u16*)(w + 50331648);    // (B,H,DK,VST) bf16 padded: 8,912,896 B
    u16* Ob  = (u16*)(w + 59244544);    // 8 MiB (B,S,H*DK) bf16

    conv_all<<<16384, 256, 0, stream>>>(v, k, qq, Wv, Wk, Wq, Wo, cvtb);
    proj_gemm<<<dim3(8, 32, 3), 256, 0, stream>>>(cvtb, cvtb + 12582912,
                                                  bv, bk, bq, v2, k2, q2T);
    flash_attn<<<256, 512, 0, stream>>>(v2, k2, q2T, Ob);
    out_gemm<<<dim3(16, 32), 256, 0, stream>>>(Ob, cvtb + 15728640, bo, out);
}